// Round 6
// baseline (69.916 us; speedup 1.0000x reference)
//
#include <hip/hip_runtime.h>
#include <math.h>

#define HDIM 512
#define LDIM 256
#define NBLK 16   // each block: full gather + full t + 32 out rows

__device__ __forceinline__ void fma4(float4& a, float w, const float4& e) {
    a.x += w * e.x; a.y += w * e.y; a.z += w * e.z; a.w += w * e.w;
}

// Single plain kernel, 16 blocks x 512 threads. No inter-block communication.
// Phase A: blend weights + loc -> LDS.
// Phase B: redundant gather-sum s (4 x 512) via 4 groups x 64 rows, LDS reduce.
// Phase C: full t (t_up,t_lo in R^512), one t-row PAIR per thread (i = tid),
//          weights read per-thread-contiguous, s broadcast from LDS.
// Phase D: 32 output rows per block (4 per wave), all loads batched.
__global__ void __launch_bounds__(512)
strnn_single(const float* __restrict__ td_u, const float* __restrict__ td_l,
             const float* __restrict__ ld_u, const float* __restrict__ ld_l,
             const float* __restrict__ hx,   const float* __restrict__ W_ih,
             const float* __restrict__ W_thU, const float* __restrict__ W_thL,
             const float* __restrict__ W_shU, const float* __restrict__ W_shL,
             const float* __restrict__ table, const int* __restrict__ loc,
             float* __restrict__ out)
{
    __shared__ float4 w_s[LDIM];          // 4 KB
    __shared__ int    loc_s[LDIM];        // 1 KB
    __shared__ float  part[4][4 * HDIM];  // 32 KB
    __shared__ float  s_sm[4 * HDIM];     // 8 KB
    __shared__ float  t_up[HDIM];         // 2 KB
    __shared__ float  t_lo[HDIM];         // 2 KB
    const int tid  = threadIdx.x;
    const int wave = tid >> 6;
    const int lane = tid & 63;
    const int b    = blockIdx.x;

    // ---- A: per-l blend weights + indices ----
    if (tid < LDIM) {
        const int l = tid;
        const float a1 = td_u[l], b1 = td_l[l];
        const float beta = a1 / (a1 + b1);
        const float a2 = ld_u[l], b2 = ld_l[l];
        const float alpha = a2 / (a2 + b2);
        w_s[l] = make_float4(alpha * beta, alpha * (1.0f - beta),
                             (1.0f - alpha) * beta, (1.0f - alpha) * (1.0f - beta));
        loc_s[l] = loc[l];
    }
    __syncthreads();

    // ---- B: gather, group g of 4 sums rows [g*64, g*64+64) ----
    {
        const int g  = tid >> 7;
        const int c  = tid & 127;
        const int h4 = c * 4;
        const int lbase = g * 64;
        float4 a0 = {0,0,0,0}, a1v = {0,0,0,0}, a2v = {0,0,0,0}, a3v = {0,0,0,0};
        for (int base = 0; base < 64; base += 16) {
            float4 e[16];
#pragma unroll
            for (int k = 0; k < 16; ++k)
                e[k] = *(const float4*)(table + (size_t)loc_s[lbase + base + k] * HDIM + h4);
#pragma unroll
            for (int k = 0; k < 16; ++k) {
                const float4 w = w_s[lbase + base + k];
                fma4(a0,  w.x, e[k]);
                fma4(a1v, w.y, e[k]);
                fma4(a2v, w.z, e[k]);
                fma4(a3v, w.w, e[k]);
            }
        }
        *(float4*)(&part[g][0 * HDIM + h4]) = a0;
        *(float4*)(&part[g][1 * HDIM + h4]) = a1v;
        *(float4*)(&part[g][2 * HDIM + h4]) = a2v;
        *(float4*)(&part[g][3 * HDIM + h4]) = a3v;
    }
    __syncthreads();
    {
        const int s0 = tid * 4;
        float4 r = {0,0,0,0};
#pragma unroll
        for (int p = 0; p < 4; ++p) {
            const float4 v = *(const float4*)(&part[p][s0]);
            r.x += v.x; r.y += v.y; r.z += v.z; r.w += v.w;
        }
        *(float4*)(&s_sm[s0]) = r;
    }
    __syncthreads();

    // ---- C: full t, thread owns row i = tid ----
    {
        const int i = tid;
        const float* wu = W_thU + (size_t)i * HDIM;
        const float* wl = W_thL + (size_t)i * HDIM;
        float tu = 0.f, tl = 0.f;
        for (int j0 = 0; j0 < HDIM; j0 += 32) {   // 16 outer, 8 float4 steps inner
            float4 eu[8], el[8];
#pragma unroll
            for (int k = 0; k < 8; ++k) {
                eu[k] = *(const float4*)(wu + j0 + k * 4);
                el[k] = *(const float4*)(wl + j0 + k * 4);
            }
#pragma unroll
            for (int k = 0; k < 8; ++k) {
                const int j = j0 + k * 4;
                const float4 s1 = *(const float4*)(s_sm + 0 * HDIM + j);
                const float4 s2 = *(const float4*)(s_sm + 1 * HDIM + j);
                const float4 s3 = *(const float4*)(s_sm + 2 * HDIM + j);
                const float4 s4 = *(const float4*)(s_sm + 3 * HDIM + j);
                tu += eu[k].x * s1.x + eu[k].y * s1.y + eu[k].z * s1.z + eu[k].w * s1.w
                    + el[k].x * s2.x + el[k].y * s2.y + el[k].z * s2.z + el[k].w * s2.w;
                tl += eu[k].x * s3.x + eu[k].y * s3.y + eu[k].z * s3.z + eu[k].w * s3.w
                    + el[k].x * s4.x + el[k].y * s4.y + el[k].z * s4.z + el[k].w * s4.w;
            }
        }
        t_up[i] = tu;
        t_lo[i] = tl;
    }
    __syncthreads();

    // ---- D: 32 out rows/block, 4 per wave, loads batched up front ----
    {
        const int r0 = b * 32 + wave * 4;   // rows r0..r0+3
        float4 WU[4][2], WL[4][2], WI[4][2];
#pragma unroll
        for (int q = 0; q < 4; ++q) {
            const size_t row = (size_t)(r0 + q) * HDIM;
#pragma unroll
            for (int it = 0; it < 2; ++it) {
                const int j = it * 256 + lane * 4;
                WU[q][it] = *(const float4*)(W_shU + row + j);
                WL[q][it] = *(const float4*)(W_shL + row + j);
                WI[q][it] = *(const float4*)(W_ih + row + j);
            }
        }
        float4 TU[2], TL[2], HV[2];
#pragma unroll
        for (int it = 0; it < 2; ++it) {
            const int j = it * 256 + lane * 4;
            TU[it] = *(const float4*)(t_up + j);
            TL[it] = *(const float4*)(t_lo + j);
            HV[it] = *(const float4*)(hx + j);
        }
#pragma unroll
        for (int q = 0; q < 4; ++q) {
            float p = 0.f;
#pragma unroll
            for (int it = 0; it < 2; ++it) {
                p += WU[q][it].x * TU[it].x + WU[q][it].y * TU[it].y
                   + WU[q][it].z * TU[it].z + WU[q][it].w * TU[it].w
                   + WL[q][it].x * TL[it].x + WL[q][it].y * TL[it].y
                   + WL[q][it].z * TL[it].z + WL[q][it].w * TL[it].w
                   + WI[q][it].x * HV[it].x + WI[q][it].y * HV[it].y
                   + WI[q][it].z * HV[it].z + WI[q][it].w * HV[it].w;
            }
#pragma unroll
            for (int off = 32; off; off >>= 1) p += __shfl_down(p, off);
            if (lane == 0) out[r0 + q] = 1.0f / (1.0f + expf(-p));
        }
    }
}

extern "C" void kernel_launch(void* const* d_in, const int* in_sizes, int n_in,
                              void* d_out, int out_size, void* d_ws, size_t ws_size,
                              hipStream_t stream) {
    const float* td_u  = (const float*)d_in[0];
    const float* td_l  = (const float*)d_in[1];
    const float* ld_u  = (const float*)d_in[2];
    const float* ld_l  = (const float*)d_in[3];
    const float* hx    = (const float*)d_in[4];
    const float* W_ih  = (const float*)d_in[5];
    const float* W_thU = (const float*)d_in[6];
    const float* W_thL = (const float*)d_in[7];
    const float* W_shU = (const float*)d_in[8];
    const float* W_shL = (const float*)d_in[9];
    const float* table = (const float*)d_in[10];
    const int*   loc   = (const int*)d_in[11];

    float* out = (float*)d_out;

    strnn_single<<<NBLK, 512, 0, stream>>>(td_u, td_l, ld_u, ld_l, hx, W_ih,
                                           W_thU, W_thL, W_shU, W_shL,
                                           table, loc, out);
}

// Round 7
// 15.362 us; speedup vs baseline: 4.5513x; 4.5513x over previous
//
#include <hip/hip_runtime.h>
#include <math.h>

#define HDIM 512
#define LDIM 256
#define NB1 16    // stage-1 blocks: gather redundancy = NB1 * 512 KB

__device__ __forceinline__ void fma4(float4& a, float w, const float4& e) {
    a.x += w * e.x; a.y += w * e.y; a.z += w * e.z; a.w += w * e.w;
}

// Node 1: 16 blocks x 512 threads (8 waves).
// Each block redundantly computes s = 4 weighted gather-sums (full 256 rows,
// coalesced float4, 16 loads in flight), then 32 t-rows (4 per wave,
// lanes span columns -> coalesced; W_th read once in aggregate).
__global__ void __launch_bounds__(512)
k_stage1(const float* __restrict__ td_u, const float* __restrict__ td_l,
         const float* __restrict__ ld_u, const float* __restrict__ ld_l,
         const float* __restrict__ table, const int* __restrict__ loc,
         const float* __restrict__ W_thU, const float* __restrict__ W_thL,
         float* __restrict__ t /* 2*HDIM */) {
    __shared__ float4 w_s[LDIM];          // 4 KB
    __shared__ int    loc_s[LDIM];        // 1 KB
    __shared__ float  part[4][4 * HDIM];  // 32 KB
    __shared__ float  s_sm[4 * HDIM];     // 8 KB
    const int tid  = threadIdx.x;
    const int wave = tid >> 6;
    const int lane = tid & 63;

    if (tid < LDIM) {
        const int l = tid;
        const float a1 = td_u[l], b1 = td_l[l];
        const float beta = a1 / (a1 + b1);
        const float a2 = ld_u[l], b2 = ld_l[l];
        const float alpha = a2 / (a2 + b2);
        w_s[l] = make_float4(alpha * beta, alpha * (1.0f - beta),
                             (1.0f - alpha) * beta, (1.0f - alpha) * (1.0f - beta));
        loc_s[l] = loc[l];
    }
    __syncthreads();

    // ---- gather: group g (of 4) sums rows [g*64, g*64+64), float4 cols ----
    {
        const int g  = tid >> 7;
        const int c  = tid & 127;
        const int h4 = c * 4;
        const int lbase = g * 64;
        float4 a0 = {0,0,0,0}, a1v = {0,0,0,0}, a2v = {0,0,0,0}, a3v = {0,0,0,0};
        for (int base = 0; base < 64; base += 16) {
            float4 e[16];
#pragma unroll
            for (int k = 0; k < 16; ++k)
                e[k] = *(const float4*)(table + (size_t)loc_s[lbase + base + k] * HDIM + h4);
#pragma unroll
            for (int k = 0; k < 16; ++k) {
                const float4 w = w_s[lbase + base + k];
                fma4(a0,  w.x, e[k]);
                fma4(a1v, w.y, e[k]);
                fma4(a2v, w.z, e[k]);
                fma4(a3v, w.w, e[k]);
            }
        }
        *(float4*)(&part[g][0 * HDIM + h4]) = a0;
        *(float4*)(&part[g][1 * HDIM + h4]) = a1v;
        *(float4*)(&part[g][2 * HDIM + h4]) = a2v;
        *(float4*)(&part[g][3 * HDIM + h4]) = a3v;
    }
    __syncthreads();

    // ---- reduce 4 group-partials into s_sm ----
    {
        const int s0 = tid * 4;
        float4 r = {0,0,0,0};
#pragma unroll
        for (int p = 0; p < 4; ++p) {
            const float4 v = *(const float4*)(&part[p][s0]);
            r.x += v.x; r.y += v.y; r.z += v.z; r.w += v.w;
        }
        *(float4*)(&s_sm[s0]) = r;
    }
    __syncthreads();

    // ---- t rows: 4 per wave (coalesced: lanes span columns), batched loads --
    {
        const int r0 = blockIdx.x * 32 + wave * 4;
        float4 WU[4][2], WL[4][2];
#pragma unroll
        for (int q = 0; q < 4; ++q) {
            const size_t row = (size_t)(r0 + q) * HDIM;
#pragma unroll
            for (int it = 0; it < 2; ++it) {
                const int j = it * 256 + lane * 4;
                WU[q][it] = *(const float4*)(W_thU + row + j);
                WL[q][it] = *(const float4*)(W_thL + row + j);
            }
        }
        float4 S1[2], S2[2], S3[2], S4[2];
#pragma unroll
        for (int it = 0; it < 2; ++it) {
            const int j = it * 256 + lane * 4;
            S1[it] = *(const float4*)(s_sm + 0 * HDIM + j);
            S2[it] = *(const float4*)(s_sm + 1 * HDIM + j);
            S3[it] = *(const float4*)(s_sm + 2 * HDIM + j);
            S4[it] = *(const float4*)(s_sm + 3 * HDIM + j);
        }
#pragma unroll
        for (int q = 0; q < 4; ++q) {
            float pu = 0.f, pl = 0.f;
#pragma unroll
            for (int it = 0; it < 2; ++it) {
                pu += WU[q][it].x * S1[it].x + WU[q][it].y * S1[it].y
                    + WU[q][it].z * S1[it].z + WU[q][it].w * S1[it].w
                    + WL[q][it].x * S2[it].x + WL[q][it].y * S2[it].y
                    + WL[q][it].z * S2[it].z + WL[q][it].w * S2[it].w;
                pl += WU[q][it].x * S3[it].x + WU[q][it].y * S3[it].y
                    + WU[q][it].z * S3[it].z + WU[q][it].w * S3[it].w
                    + WL[q][it].x * S4[it].x + WL[q][it].y * S4[it].y
                    + WL[q][it].z * S4[it].z + WL[q][it].w * S4[it].w;
            }
#pragma unroll
            for (int off = 32; off; off >>= 1) {
                pu += __shfl_down(pu, off);
                pl += __shfl_down(pl, off);
            }
            if (lane == 0) { t[r0 + q] = pu; t[HDIM + r0 + q] = pl; }
        }
    }
}

// Node 2: out[i] = sigmoid( W_shU[i,:]·t_up + W_shL[i,:]·t_lo + W_ih[i,:]·hx )
__global__ void __launch_bounds__(256)
k_out(const float* __restrict__ WshU, const float* __restrict__ WshL,
      const float* __restrict__ Wih, const float* __restrict__ t,
      const float* __restrict__ hx, float* __restrict__ out) {
    const int wave = threadIdx.x >> 6;
    const int lane = threadIdx.x & 63;
    const int i = blockIdx.x * 4 + wave;
    const float* wu = WshU + (size_t)i * HDIM;
    const float* wl = WshL + (size_t)i * HDIM;
    const float* wi = Wih + (size_t)i * HDIM;
    float p = 0.f;
#pragma unroll
    for (int it = 0; it < 2; ++it) {
        const int j = it * 256 + lane * 4;
        const float4 u   = *(const float4*)(wu + j);
        const float4 l4  = *(const float4*)(wl + j);
        const float4 wi4 = *(const float4*)(wi + j);
        const float4 tu  = *(const float4*)(t + j);
        const float4 tl  = *(const float4*)(t + HDIM + j);
        const float4 hv  = *(const float4*)(hx + j);
        p += u.x * tu.x + u.y * tu.y + u.z * tu.z + u.w * tu.w
           + l4.x * tl.x + l4.y * tl.y + l4.z * tl.z + l4.w * tl.w
           + wi4.x * hv.x + wi4.y * hv.y + wi4.z * hv.z + wi4.w * hv.w;
    }
#pragma unroll
    for (int off = 32; off; off >>= 1) p += __shfl_down(p, off);
    if (lane == 0) out[i] = 1.0f / (1.0f + expf(-p));
}

extern "C" void kernel_launch(void* const* d_in, const int* in_sizes, int n_in,
                              void* d_out, int out_size, void* d_ws, size_t ws_size,
                              hipStream_t stream) {
    const float* td_u  = (const float*)d_in[0];
    const float* td_l  = (const float*)d_in[1];
    const float* ld_u  = (const float*)d_in[2];
    const float* ld_l  = (const float*)d_in[3];
    const float* hx    = (const float*)d_in[4];
    const float* W_ih  = (const float*)d_in[5];
    const float* W_thU = (const float*)d_in[6];
    const float* W_thL = (const float*)d_in[7];
    const float* W_shU = (const float*)d_in[8];
    const float* W_shL = (const float*)d_in[9];
    const float* table = (const float*)d_in[10];
    const int*   loc   = (const int*)d_in[11];

    float* t   = (float*)d_ws;   // 2*HDIM intermediate (fully rewritten each call)
    float* out = (float*)d_out;

    k_stage1<<<NB1, 512, 0, stream>>>(td_u, td_l, ld_u, ld_l, table, loc,
                                      W_thU, W_thL, t);
    k_out<<<HDIM / 4, 256, 0, stream>>>(W_shU, W_shL, W_ih, t, hx, out);
}